// Round 7
// baseline (149.601 us; speedup 1.0000x reference)
//
#include <hip/hip_runtime.h>

// SVD_Solver: weighted Kabsch per (batch, joint).  B=4096, M=64, J=24.
// Round 10b: resubmit of R10 (R6 bench was an infra failure, same class as
// R4; kernel audited: aligned float2s, bounds-safe, 1 barrier).
// Joint-pair vectorized loads. R9b (wave-per-batch, 224 scalar loads/lane)
// reached ~44us; surviving bottleneck theory = VMEM issue + L1-transaction
// cost of the scattered scalar stream at unramped clock.
// Lane map: lane=(jp,kq), jp in [0,12) owns joints {2jp,2jp+1}, kq in [0,4)
// owns m = i*4+kq (16 iters). Per iter: w as 1x float2 (8B aligned), o as
// 3x float2 (covers BOTH joints' 3-vectors, contiguous), p as 3 scalars ->
// 112 VMEM/lane (halved), ~3x fewer L1 transactions, half the addressing
// VALU. Reduce over kq: 2 shfl_xor steps. Wave-per-batch decoupling, ONE
// barrier, 48 solves on wave 0 (unchanged from R9b).

constexpr int M = 64;
constexpr int J = 24;
constexpr int NWS  = 15;          // S[9], Pbar[3], Qbar[3]
constexpr int WPB  = 2;           // waves (=batches) per block

// ---- fast Jacobi rotation: single-instruction rcp/rsq/sqrt ----
template<int P, int Q>
__device__ __forceinline__ void jrot(float A[4][4], float V[4][4]) {
    float apq = A[P][Q];
    float theta = (A[Q][Q] - A[P][P]) * __builtin_amdgcn_rcpf(2.0f * apq);
    float t = __builtin_amdgcn_rcpf(fabsf(theta) + __builtin_amdgcn_sqrtf(fmaf(theta, theta, 1.0f)));
    t = (theta < 0.0f) ? -t : t;
    t = (apq == 0.0f) ? 0.0f : t;            // kills inf/NaN from rcp(0)
    float c = __builtin_amdgcn_rsqf(fmaf(t, t, 1.0f));
    float s = t * c;
#pragma unroll
    for (int k = 0; k < 4; ++k) {
        float akp = A[k][P], akq = A[k][Q];
        A[k][P] = c * akp - s * akq;
        A[k][Q] = s * akp + c * akq;
    }
#pragma unroll
    for (int k = 0; k < 4; ++k) {
        float apk = A[P][k], aqk = A[Q][k];
        A[P][k] = c * apk - s * aqk;
        A[Q][k] = s * apk + c * aqk;
        float vkp = V[k][P], vkq = V[k][Q];
        V[k][P] = c * vkp - s * vkq;
        V[k][Q] = s * vkp + c * vkq;
    }
}

__device__ __forceinline__ void horn_solve(
    float S00, float S01, float S02, float S10, float S11, float S12,
    float S20, float S21, float S22,
    float cP0, float cP1, float cP2, float cQ0, float cQ1, float cQ2,
    float* __restrict__ Rout, float* __restrict__ tout)
{
    float A[4][4], V[4][4];
    A[0][0] = S00 + S11 + S22;
    A[0][1] = A[1][0] = S12 - S21;
    A[0][2] = A[2][0] = S20 - S02;
    A[0][3] = A[3][0] = S01 - S10;
    A[1][1] = S00 - S11 - S22;
    A[1][2] = A[2][1] = S01 + S10;
    A[1][3] = A[3][1] = S02 + S20;
    A[2][2] = -S00 + S11 - S22;
    A[2][3] = A[3][2] = S12 + S21;
    A[3][3] = -S00 - S11 + S22;
#pragma unroll
    for (int r = 0; r < 4; ++r)
#pragma unroll
        for (int c = 0; c < 4; ++c)
            V[r][c] = (r == c) ? 1.0f : 0.0f;

#pragma unroll 1
    for (int sweep = 0; sweep < 6; ++sweep) {
        jrot<0, 1>(A, V); jrot<0, 2>(A, V); jrot<0, 3>(A, V);
        jrot<1, 2>(A, V); jrot<1, 3>(A, V); jrot<2, 3>(A, V);
    }

    float best = A[0][0];
    float qw = V[0][0], qx = V[1][0], qy = V[2][0], qz = V[3][0];
#pragma unroll
    for (int i = 1; i < 4; ++i) {
        bool better = A[i][i] > best;
        best = better ? A[i][i] : best;
        qw = better ? V[0][i] : qw;
        qx = better ? V[1][i] : qx;
        qy = better ? V[2][i] : qy;
        qz = better ? V[3][i] : qz;
    }
    float nrm = __builtin_amdgcn_rsqf(qw * qw + qx * qx + qy * qy + qz * qz);
    qw *= nrm; qx *= nrm; qy *= nrm; qz *= nrm;

    float R00 = 1.f - 2.f * (qy * qy + qz * qz);
    float R01 = 2.f * (qx * qy - qw * qz);
    float R02 = 2.f * (qx * qz + qw * qy);
    float R10 = 2.f * (qx * qy + qw * qz);
    float R11 = 1.f - 2.f * (qx * qx + qz * qz);
    float R12 = 2.f * (qy * qz - qw * qx);
    float R20 = 2.f * (qx * qz - qw * qy);
    float R21 = 2.f * (qy * qz + qw * qx);
    float R22 = 1.f - 2.f * (qx * qx + qy * qy);

    Rout[0] = R00; Rout[1] = R01; Rout[2] = R02;
    Rout[3] = R10; Rout[4] = R11; Rout[5] = R12;
    Rout[6] = R20; Rout[7] = R21; Rout[8] = R22;
    tout[0] = cQ0 - (R00 * cP0 + R01 * cP1 + R02 * cP2);
    tout[1] = cQ1 - (R10 * cP0 + R11 * cP1 + R12 * cP2);
    tout[2] = cQ2 - (R20 * cP0 + R21 * cP1 + R22 * cP2);
}

// ---- wave-per-batch fused: grid = ceil(B/WPB) x 128 threads ----
__global__ __launch_bounds__(128, 4) void kabsch_fused(
    const float* __restrict__ points,   // (B, 64, 3)
    const float* __restrict__ weight,   // (B, 64, 24)
    const float* __restrict__ offset,   // (B, 64, 24, 3)
    float* __restrict__ out,            // R (bj,9) then t (bj,3)
    int B, int bj_total)
{
    const int t    = threadIdx.x;
    const int wv   = t >> 6;             // wave in block = batch slot
    const int lane = t & 63;
    const int jp   = lane >> 2;          // joint-pair 0..15 (12..15 idle)
    const int kq   = lane & 3;           // m-quarter: m = i*4 + kq

    int bw = blockIdx.x * WPB + wv;
    bw = bw < B ? bw : B - 1;            // clamp keeps wave alive for barrier

    __shared__ float sv_s[WPB][NWS][J + 1];   // 1.5 KB prepadded handoff

    if (jp < 12) {
        // all addresses 8B-aligned; per-i offsets are compile-time immediates
        const float* wq = weight + (size_t)bw * (M * J)     + kq * 24 + jp * 2;
        const float* oq = offset + (size_t)bw * (M * J * 3) + kq * 72 + jp * 6;
        const float* pq = points + (size_t)bw * (M * 3)     + kq * 3;

        // ac[jl][0]=W, [1..3]=Wo, [4..6]=Wp, [7..9]=To, [10..18]=Sraw(d*3+e)
        float ac[2][19];
        float tp0 = 0.f, tp1 = 0.f, tp2 = 0.f;
#pragma unroll
        for (int jl = 0; jl < 2; ++jl)
#pragma unroll
            for (int n = 0; n < 19; ++n) ac[jl][n] = 0.f;

#pragma unroll
        for (int i = 0; i < 16; ++i) {
            float2 w2 = *(const float2*)(wq + i * 96);        // w[m][2jp], w[m][2jp+1]
            float2 oa = *(const float2*)(oq + i * 288);       // o[m][j0][0], o[m][j0][1]
            float2 ob = *(const float2*)(oq + i * 288 + 2);   // o[m][j0][2], o[m][j1][0]
            float2 oc = *(const float2*)(oq + i * 288 + 4);   // o[m][j1][1], o[m][j1][2]
            float p0 = pq[i * 12 + 0];
            float p1 = pq[i * 12 + 1];
            float p2 = pq[i * 12 + 2];
            tp0 += p0; tp1 += p1; tp2 += p2;
            {   // joint j0 = 2*jp
                float w = w2.x, o0 = oa.x, o1 = oa.y, o2 = ob.x;
                ac[0][0] += w;
                ac[0][1] = fmaf(w, o0, ac[0][1]); ac[0][2] = fmaf(w, o1, ac[0][2]); ac[0][3] = fmaf(w, o2, ac[0][3]);
                ac[0][4] = fmaf(w, p0, ac[0][4]); ac[0][5] = fmaf(w, p1, ac[0][5]); ac[0][6] = fmaf(w, p2, ac[0][6]);
                ac[0][7] += o0; ac[0][8] += o1; ac[0][9] += o2;
                ac[0][10] = fmaf(o0, p0, ac[0][10]); ac[0][11] = fmaf(o0, p1, ac[0][11]); ac[0][12] = fmaf(o0, p2, ac[0][12]);
                ac[0][13] = fmaf(o1, p0, ac[0][13]); ac[0][14] = fmaf(o1, p1, ac[0][14]); ac[0][15] = fmaf(o1, p2, ac[0][15]);
                ac[0][16] = fmaf(o2, p0, ac[0][16]); ac[0][17] = fmaf(o2, p1, ac[0][17]); ac[0][18] = fmaf(o2, p2, ac[0][18]);
            }
            {   // joint j1 = 2*jp+1
                float w = w2.y, o0 = ob.y, o1 = oc.x, o2 = oc.y;
                ac[1][0] += w;
                ac[1][1] = fmaf(w, o0, ac[1][1]); ac[1][2] = fmaf(w, o1, ac[1][2]); ac[1][3] = fmaf(w, o2, ac[1][3]);
                ac[1][4] = fmaf(w, p0, ac[1][4]); ac[1][5] = fmaf(w, p1, ac[1][5]); ac[1][6] = fmaf(w, p2, ac[1][6]);
                ac[1][7] += o0; ac[1][8] += o1; ac[1][9] += o2;
                ac[1][10] = fmaf(o0, p0, ac[1][10]); ac[1][11] = fmaf(o0, p1, ac[1][11]); ac[1][12] = fmaf(o0, p2, ac[1][12]);
                ac[1][13] = fmaf(o1, p0, ac[1][13]); ac[1][14] = fmaf(o1, p1, ac[1][14]); ac[1][15] = fmaf(o1, p2, ac[1][15]);
                ac[1][16] = fmaf(o2, p0, ac[1][16]); ac[1][17] = fmaf(o2, p1, ac[1][17]); ac[1][18] = fmaf(o2, p2, ac[1][18]);
            }
        }

        // reduce over kq (lane bits 0..1): 2 shfl_xor steps, within jp-groups
#pragma unroll
        for (int jl = 0; jl < 2; ++jl)
#pragma unroll
            for (int n = 0; n < 19; ++n) {
                float v = ac[jl][n];
                v += __shfl_xor(v, 1);
                v += __shfl_xor(v, 2);
                ac[jl][n] = v;
            }
        tp0 += __shfl_xor(tp0, 1); tp0 += __shfl_xor(tp0, 2);
        tp1 += __shfl_xor(tp1, 1); tp1 += __shfl_xor(tp1, 2);
        tp2 += __shfl_xor(tp2, 1); tp2 += __shfl_xor(tp2, 2);

        if (kq == 0) {
            const float fM = (float)M;
#pragma unroll
            for (int jl = 0; jl < 2; ++jl) {
                const float inv = __builtin_amdgcn_rcpf(ac[jl][0]);
                const float cP0 = ac[jl][1] * inv, cP1 = ac[jl][2] * inv, cP2 = ac[jl][3] * inv;
                const float cQ0 = ac[jl][4] * inv, cQ1 = ac[jl][5] * inv, cQ2 = ac[jl][6] * inv;
                const float To0 = ac[jl][7], To1 = ac[jl][8], To2 = ac[jl][9];
                const int j = jp * 2 + jl;
                sv_s[wv][0][j]  = ac[jl][10] - cP0 * tp0 - cQ0 * To0 + fM * cP0 * cQ0;
                sv_s[wv][1][j]  = ac[jl][11] - cP0 * tp1 - cQ1 * To0 + fM * cP0 * cQ1;
                sv_s[wv][2][j]  = ac[jl][12] - cP0 * tp2 - cQ2 * To0 + fM * cP0 * cQ2;
                sv_s[wv][3][j]  = ac[jl][13] - cP1 * tp0 - cQ0 * To1 + fM * cP1 * cQ0;
                sv_s[wv][4][j]  = ac[jl][14] - cP1 * tp1 - cQ1 * To1 + fM * cP1 * cQ1;
                sv_s[wv][5][j]  = ac[jl][15] - cP1 * tp2 - cQ2 * To1 + fM * cP1 * cQ2;
                sv_s[wv][6][j]  = ac[jl][16] - cP2 * tp0 - cQ0 * To2 + fM * cP2 * cQ0;
                sv_s[wv][7][j]  = ac[jl][17] - cP2 * tp1 - cQ1 * To2 + fM * cP2 * cQ1;
                sv_s[wv][8][j]  = ac[jl][18] - cP2 * tp2 - cQ2 * To2 + fM * cP2 * cQ2;
                sv_s[wv][9][j]  = cP0; sv_s[wv][10][j] = cP1; sv_s[wv][11][j] = cP2;
                sv_s[wv][12][j] = cQ0; sv_s[wv][13][j] = cQ1; sv_s[wv][14][j] = cQ2;
            }
        }
    }

    __syncthreads();   // the ONLY barrier

    // solve phase: threads 0..47 (wave 0), one Horn solve each; wave 1 retires
    if (t < WPB * J) {
        const int g  = t / J;
        const int j  = t - g * J;
        int bb = blockIdx.x * WPB + g;
        if (bb < B) {
            float v[NWS];
#pragma unroll
            for (int n = 0; n < NWS; ++n) v[n] = sv_s[g][n][j];
            float Rr[9], tr[3];
            horn_solve(v[0], v[1], v[2], v[3], v[4], v[5], v[6], v[7], v[8],
                       v[9], v[10], v[11], v[12], v[13], v[14], Rr, tr);
            const int bj = bb * J + j;
            float* Rout = out + (size_t)bj * 9;
#pragma unroll
            for (int n = 0; n < 9; ++n) Rout[n] = Rr[n];
            float* tout = out + (size_t)bj_total * 9 + (size_t)bj * 3;
            tout[0] = tr[0]; tout[1] = tr[1]; tout[2] = tr[2];
        }
    }
}

extern "C" void kernel_launch(void* const* d_in, const int* in_sizes, int n_in,
                              void* d_out, int out_size, void* d_ws, size_t ws_size,
                              hipStream_t stream) {
    const float* points = (const float*)d_in[0];
    const float* weight = (const float*)d_in[1];
    const float* offset = (const float*)d_in[2];
    float* out = (float*)d_out;

    int B = in_sizes[0] / (M * 3);
    int bj_total = B * J;
    int grid = (B + WPB - 1) / WPB;

    kabsch_fused<<<grid, 128, 0, stream>>>(points, weight, offset, out, B, bj_total);
}